// Round 14
// baseline (609.232 us; speedup 1.0000x reference)
//
#include <hip/hip_runtime.h>
#include <cstdint>
#include <cstddef>

#define N_POINTS 32768
#define KDEG 16
#define N_EDGES (N_POINTS*KDEG)
#define BATCH 2
#define HID 64
#define LIFTD 256
#define PROJD 256
#define KIN 68
#define NLAYERS 4

#define DSTS 32          // dst nodes per block (exclusively owned -> LDS-only aggregation)
#define LK_WAVES 4
#define GSTR 72          // ushort stride of layer G tile rows (144 B); cols XOR-swizzled
#define MSTR 66          // float stride of M tile (66%8==2 -> writes <=2-way, reads 2-way: free)

#define LASTR 40         // lift A tile stride
#define LGSTR 264        // lift G tile stride

#define FR_EDGE 0        // 80 frags (4 layers x 20): B-operand edge-MLP weights
#define FR_LW1  80       // 16 frags: lift W1'
#define FR_LW2  96       // 32 frags: lift W2'
#define FR_TOT  128      // 128KB == cursor region exactly

typedef unsigned short ushort_t;
typedef short short8 __attribute__((ext_vector_type(8)));
typedef float floatx4 __attribute__((ext_vector_type(4)));

union frag_u { uint4 u; short8 s; };

// tanh-form GELU with HW approx reciprocal (validated R11)
__device__ __forceinline__ float gelu_fast(float x) {
    float t = x * x;
    float inner = x * fmaf(0.044715f, t, 1.0f);
    float e = __expf(-1.5957691216f * inner);
#if __has_builtin(__builtin_amdgcn_rcpf)
    return x * __builtin_amdgcn_rcpf(1.0f + e);
#else
    return x * __frcp_rn(1.0f + e);
#endif
}

// round-half-up bf16 (2 ops; validated R12)
__device__ __forceinline__ ushort_t f2bf(float x) {
    return (ushort_t)((__float_as_uint(x) + 0x8000u) >> 16);
}
__device__ __forceinline__ unsigned int pk2bf(float a, float b) {
    return (unsigned int)f2bf(a) | ((unsigned int)f2bf(b) << 16);
}

// ---------------- CSR build ----------------
__global__ void hist_kernel(const int* __restrict__ ei, int* __restrict__ counts) {
    int e = blockIdx.x * 256 + threadIdx.x;
    if (e < N_EDGES) atomicAdd(&counts[ei[N_EDGES + e]], 1);
}

__global__ void scan_kernel(const int* __restrict__ counts, int* __restrict__ row_start) {
    __shared__ int sums[1024];
    const int tid = threadIdx.x;
    const int base = tid * 32;
    int s = 0;
    for (int i = 0; i < 32; ++i) s += counts[base + i];
    sums[tid] = s;
    __syncthreads();
    const int own = s;
    for (int off = 1; off < 1024; off <<= 1) {
        int v = (tid >= off) ? sums[tid - off] : 0;
        __syncthreads();
        sums[tid] += v;
        __syncthreads();
    }
    int run = sums[tid] - own;
    for (int i = 0; i < 32; ++i) { row_start[base + i] = run; run += counts[base + i]; }
    if (tid == 1023) row_start[N_POINTS] = N_EDGES;
}

__global__ void fill_kernel(const int* __restrict__ ei, const int* __restrict__ row_start,
                            int* __restrict__ cursor, int2* __restrict__ csr_pair) {
    int e = blockIdx.x * 256 + threadIdx.x;
    if (e < N_EDGES) {
        int s = ei[e], d = ei[N_EDGES + e];
        int p = atomicAdd(&cursor[d], 1);
        csr_pair[row_start[d] + p] = make_int2(s, d);
    }
}

// -------- weight pre-swizzle (bf16), B-operand layout (validated R7/R8) --------
__global__ void wprep_kernel(const float* __restrict__ kW1, const float* __restrict__ kb1,
                             const float* __restrict__ kW2,
                             const float* __restrict__ lw1, const float* __restrict__ lb1,
                             const float* __restrict__ lw2,
                             ushort_t* __restrict__ wfrag) {
    int t = blockIdx.x * 256 + threadIdx.x;
    if (t >= FR_TOT * 64) return;
    const int lane = t & 63;
    const int fi = t >> 6;
    const int m16 = lane & 15;
    const int qb = ((lane >> 4) & 3) * 8;
    ushort_t o[8];
    if (fi < FR_LW1) {
        const int l = fi / 20, f = fi % 20;
        const int n = ((f < 12 ? (f & 3) : ((f - 12) & 3)) * 16) + m16;
        if (f < 12) {
            const int kc = f >> 2;
            const float* W1 = kW1 + (size_t)l * KIN * HID;
            const float* B1 = kb1 + (size_t)l * HID;
#pragma unroll
            for (int j = 0; j < 8; ++j) {
                const int k = kc * 32 + qb + j;
                float v;
                if (k < 64) v = W1[(size_t)(4 + k) * HID + n];
                else if (k < 68) v = W1[(size_t)(k - 64) * HID + n];
                else if (k == 68) v = B1[n];
                else v = 0.f;
                o[j] = f2bf(v);
            }
        } else {
            const int kc = (f - 12) >> 2;
            const float* W2 = kW2 + (size_t)l * HID * HID;
#pragma unroll
            for (int j = 0; j < 8; ++j)
                o[j] = f2bf(W2[(size_t)(kc * 32 + qb + j) * HID + n]);
        }
    } else if (fi < FR_LW2) {
        const int ct = fi - FR_LW1;
        const int n = ct * 16 + m16;
#pragma unroll
        for (int j = 0; j < 8; ++j) {
            const int k = qb + j;
            float v;
            if (k < 5) v = lw1[(size_t)k * LIFTD + n];
            else if (k == 5) v = lb1[n];
            else v = 0.f;
            o[j] = f2bf(v);
        }
    } else {
        const int idx = fi - FR_LW2;
        const int kc = idx >> 2, ct = idx & 3;
        const int n = ct * 16 + m16;
#pragma unroll
        for (int j = 0; j < 8; ++j)
            o[j] = f2bf(lw2[(size_t)(kc * 32 + qb + j) * HID + n]);
    }
    ushort_t* dst = wfrag + ((size_t)fi * 64 + lane) * 8;
#pragma unroll
    for (int j = 0; j < 8; ++j) dst[j] = o[j];
}

__global__ void wprep_proj_kernel(const float* __restrict__ pw1, ushort_t* __restrict__ pfrag) {
    int t = blockIdx.x * 256 + threadIdx.x;
    if (t >= 32 * 64) return;
    const int lane = t & 63;
    const int fi = t >> 6;
    const int kc = fi >> 4, ct = fi & 15;
    const int n = ct * 16 + (lane & 15);
    const int qb = ((lane >> 4) & 3) * 8;
    ushort_t* dst = pfrag + ((size_t)fi * 64 + lane) * 8;
#pragma unroll
    for (int j = 0; j < 8; ++j)
        dst[j] = f2bf(pw1[(size_t)(kc * 32 + qb + j) * PROJD + n]);
}

// ---------------- lift (MFMA): 2 row-groups per block, 512 blocks ----------------
__global__ __launch_bounds__(256) void lift_kernel(
    const float* __restrict__ x, const float* __restrict__ pos,
    const ushort_t* __restrict__ wfrag, const float* __restrict__ lb2,
    float* __restrict__ hres, ushort_t* __restrict__ hb16)
{
    __shared__ __align__(16) ushort_t WF[3072 * 8];
    __shared__ __align__(16) ushort_t LA[4][16 * LASTR];
    __shared__ __align__(16) ushort_t LG[4][16 * LGSTR];

    const int tid = threadIdx.x;
    const int wv = tid >> 6;
    const int lane = tid & 63;
    const int m16 = lane & 15;
    const int q = lane >> 4;

    {
        const uint4* gw = (const uint4*)(wfrag + (size_t)FR_LW1 * 64 * 8);
        uint4* lw = (uint4*)WF;
        for (int i = tid; i < 3072; i += 256) lw[i] = gw[i];
    }
    __syncthreads();

    ushort_t* At = &LA[wv][0];
    ushort_t* Gt = &LG[wv][0];

    float b2r[4];
#pragma unroll
    for (int ct = 0; ct < 4; ++ct) b2r[ct] = lb2[ct * 16 + m16];

    for (int grp = 0; grp < 2; ++grp) {
        const int gid0 = (blockIdx.x * 8 + wv * 2 + grp) * 16;

        if (lane < 16) {
            const int g = gid0 + lane;
            const int i = g & (N_POINTS - 1);
            const float x0 = x[3 * (size_t)g], x1 = x[3 * (size_t)g + 1], x2 = x[3 * (size_t)g + 2];
            const float2 p = *(const float2*)(pos + 2 * i);
            uint4 w;
            w.x = pk2bf(x0, x1);
            w.y = pk2bf(x2, p.x);
            w.z = pk2bf(p.y, 1.0f);
            w.w = 0u;
            uint4 z; z.x = z.y = z.z = z.w = 0u;
            *(uint4*)&At[lane * LASTR + 0] = w;
            *(uint4*)&At[lane * LASTR + 8] = z;
            *(uint4*)&At[lane * LASTR + 16] = z;
            *(uint4*)&At[lane * LASTR + 24] = z;
        }

        const short8 a = *(const short8*)&At[m16 * LASTR + q * 8];
        floatx4 acc[16];
#pragma unroll
        for (int ct = 0; ct < 16; ++ct) {
            const short8 bf = *(const short8*)&WF[((size_t)ct * 64 + lane) * 8];
            floatx4 c = {0.f, 0.f, 0.f, 0.f};
            acc[ct] = __builtin_amdgcn_mfma_f32_16x16x32_bf16(a, bf, c, 0, 0, 0);
        }

#pragma unroll
        for (int ct = 0; ct < 16; ++ct)
#pragma unroll
            for (int r = 0; r < 4; ++r)
                Gt[(q * 4 + r) * LGSTR + ct * 16 + m16] = f2bf(gelu_fast(acc[ct][r]));

        floatx4 acc2[4];
#pragma unroll
        for (int ct = 0; ct < 4; ++ct) { floatx4 z = {0.f, 0.f, 0.f, 0.f}; acc2[ct] = z; }
#pragma unroll
        for (int kc = 0; kc < 8; ++kc) {
            const short8 g = *(const short8*)&Gt[m16 * LGSTR + kc * 32 + q * 8];
#pragma unroll
            for (int ct = 0; ct < 4; ++ct) {
                const short8 bf = *(const short8*)&WF[((size_t)(1024 + (kc * 4 + ct) * 64) + lane) * 8];
                acc2[ct] = __builtin_amdgcn_mfma_f32_16x16x32_bf16(g, bf, acc2[ct], 0, 0, 0);
            }
        }

#pragma unroll
        for (int ct = 0; ct < 4; ++ct)
#pragma unroll
            for (int r = 0; r < 4; ++r) {
                const float v = acc2[ct][r] + b2r[ct];
                const size_t idx = (size_t)(gid0 + q * 4 + r) * HID + ct * 16 + m16;
                hres[idx] = v;
                hb16[idx] = f2bf(v);
            }
    }
}

// ------- message-passing layer: R12 structure + corrected XOR-swizzled G tile -------
__global__ __launch_bounds__(256, 4) void layer_kernel(
    float* __restrict__ hres,
    const ushort_t* __restrict__ hb_in,
    ushort_t* __restrict__ hb_out,
    const float* __restrict__ pos,
    const int2* __restrict__ csr_pair,
    const int* __restrict__ row_start, const int* __restrict__ counts,
    const ushort_t* __restrict__ wfrag, const float* __restrict__ B2)
{
    __shared__ __align__(16) float GMt[LK_WAVES][16 * MSTR];   // 16.9 KB (G bf16 overlays M f32)
    __shared__ float hacc[DSTS * HID];                         // 8 KB
    __shared__ int   segb[LK_WAVES][16];

    const int b = blockIdx.y;
    const int dstBase = blockIdx.x * DSTS;
    const int tid = threadIdx.x;
    const int wv = tid >> 6;
    const int lane = tid & 63;
    const int m16 = lane & 15;
    const int q = lane >> 4;
    const int ch = lane & 3;
    const int growL = lane >> 2;
    const int permSrc = m16 * 4 + q;

    for (int i = tid; i < DSTS * HID; i += 256) hacc[i] = 0.f;

    const short8* wf = (const short8*)wfrag;
    short8 w1f[3][4], w2f[2][4];
#pragma unroll
    for (int kc = 0; kc < 3; ++kc)
#pragma unroll
        for (int ct = 0; ct < 4; ++ct) w1f[kc][ct] = wf[(kc * 4 + ct) * 64 + lane];
#pragma unroll
    for (int kc = 0; kc < 2; ++kc)
#pragma unroll
        for (int ct = 0; ct < 4; ++ct) w2f[kc][ct] = wf[(12 + kc * 4 + ct) * 64 + lane];
    __syncthreads();

    const int estart = row_start[dstBase];
    const int eend   = row_start[dstBase + DSTS];
    const int ntiles = (eend - estart + 15) >> 4;
    const int elast  = (eend > 0) ? (eend - 1) : 0;
    const ushort_t* __restrict__ hb = hb_in + (size_t)b * N_POINTS * HID;

    float* GM = &GMt[wv][0];
    ushort_t* Gt = (ushort_t*)GM;
    // XOR-swizzle for Gt columns: physical col = col ^ (((row>>2)&3)<<4).
    // Write: row=q*4+r -> swz=q<<4 (applied to logical col ct*16+m16).
    // Read: row=m16 -> swz=((m16>>2)&3)<<4, applied to the FULL logical start
    // of each 8-block (q*8 and 32+q*8) -- NOT added after the XOR (R13 bug).
    const int gwz = q << 4;
    const int rswz = ((m16 >> 2) & 3) << 4;
    const int grd0 = m16 * GSTR + ((q * 8) ^ rswz);
    const int grd1 = m16 * GSTR + ((32 + q * 8) ^ rswz);

    frag_u hC0, hC1; uint4 pwC; int segC;
    {
        const int e0 = estart + wv * 16;
        const int2 pA = csr_pair[min(e0 + growL, elast)];
        const int2 pB = csr_pair[min(e0 + m16, elast)];
        const uint4* hr = (const uint4*)(hb + (size_t)pA.x * HID);
        hC0.u = hr[ch];
        hC1.u = hr[ch + 4];
        const float2 ps = *(const float2*)(pos + 2 * pB.x);
        const float2 pd = *(const float2*)(pos + 2 * pB.y);
        pwC.x = pk2bf(ps.x, ps.y);
        pwC.y = pk2bf(pd.x, pd.y);
        pwC.z = 0x00003F80u;   // (1.0, 0)
        pwC.w = 0u;
        segC = (e0 + m16 < eend) ? (pB.y - dstBase) : -1;
    }

    for (int t = wv; t < ntiles; t += LK_WAVES) {
        frag_u hN0, hN1; uint4 pwN; int segN;
        {
            const int e0n = estart + (t + LK_WAVES) * 16;
            const int2 pA = csr_pair[min(e0n + growL, elast)];
            const int2 pB = csr_pair[min(e0n + m16, elast)];
            const uint4* hr = (const uint4*)(hb + (size_t)pA.x * HID);
            hN0.u = hr[ch];
            hN1.u = hr[ch + 4];
            const float2 ps = *(const float2*)(pos + 2 * pB.x);
            const float2 pd = *(const float2*)(pos + 2 * pB.y);
            pwN.x = pk2bf(ps.x, ps.y);
            pwN.y = pk2bf(pd.x, pd.y);
            pwN.z = 0x00003F80u;
            pwN.w = 0u;
            segN = (e0n + m16 < eend) ? (pB.y - dstBase) : -1;
        }

        if (lane < 16) segb[wv][lane] = segC;

        frag_u a0, a1, a2;
        a0.u.x = (unsigned)__shfl((int)hC0.u.x, permSrc);
        a0.u.y = (unsigned)__shfl((int)hC0.u.y, permSrc);
        a0.u.z = (unsigned)__shfl((int)hC0.u.z, permSrc);
        a0.u.w = (unsigned)__shfl((int)hC0.u.w, permSrc);
        a1.u.x = (unsigned)__shfl((int)hC1.u.x, permSrc);
        a1.u.y = (unsigned)__shfl((int)hC1.u.y, permSrc);
        a1.u.z = (unsigned)__shfl((int)hC1.u.z, permSrc);
        a1.u.w = (unsigned)__shfl((int)hC1.u.w, permSrc);
        if (q == 0) { a2.u = pwC; }
        else        { a2.u.x = 0u; a2.u.y = 0u; a2.u.z = 0u; a2.u.w = 0u; }

        floatx4 acc[4];
#pragma unroll
        for (int ct = 0; ct < 4; ++ct) {
            floatx4 c = {0.f, 0.f, 0.f, 0.f};
            c = __builtin_amdgcn_mfma_f32_16x16x32_bf16(a0.s, w1f[0][ct], c, 0, 0, 0);
            c = __builtin_amdgcn_mfma_f32_16x16x32_bf16(a1.s, w1f[1][ct], c, 0, 0, 0);
            c = __builtin_amdgcn_mfma_f32_16x16x32_bf16(a2.s, w1f[2][ct], c, 0, 0, 0);
            acc[ct] = c;
        }

        // gelu -> G (bf16, XOR-swizzled cols: 4 q-quadrants hit distinct banks)
#pragma unroll
        for (int ct = 0; ct < 4; ++ct)
#pragma unroll
            for (int r = 0; r < 4; ++r)
                Gt[(q * 4 + r) * GSTR + ((ct * 16 + m16) ^ gwz)] = f2bf(gelu_fast(acc[ct][r]));

        short8 g0 = *(const short8*)&Gt[grd0];
        short8 g1 = *(const short8*)&Gt[grd1];
        floatx4 mm[4];
#pragma unroll
        for (int ct = 0; ct < 4; ++ct) {
            floatx4 c = {0.f, 0.f, 0.f, 0.f};
            c = __builtin_amdgcn_mfma_f32_16x16x32_bf16(g0, w2f[0][ct], c, 0, 0, 0);
            c = __builtin_amdgcn_mfma_f32_16x16x32_bf16(g1, w2f[1][ct], c, 0, 0, 0);
            mm[ct] = c;
        }

#pragma unroll
        for (int ct = 0; ct < 4; ++ct)
#pragma unroll
            for (int r = 0; r < 4; ++r)
                GM[(q * 4 + r) * MSTR + ct * 16 + m16] = mm[ct][r];

        {
            float racc = 0.f;
            int rseg = -1;
#pragma unroll
            for (int r = 0; r < 16; ++r) {
                const int s = segb[wv][r];
                const float v = GM[r * MSTR + lane];
                if (s != rseg) {
                    if (rseg >= 0) atomicAdd(&hacc[rseg * HID + lane], racc);
                    rseg = s;
                    racc = v;
                } else {
                    racc += v;
                }
            }
            if (rseg >= 0) atomicAdd(&hacc[rseg * HID + lane], racc);
        }

        hC0 = hN0; hC1 = hN1; pwC = pwN; segC = segN;
    }
    __syncthreads();

    const size_t rowbase = (size_t)b * N_POINTS * HID;
    for (int i = tid; i < DSTS * HID; i += 256) {
        const int dl = i >> 6, c = i & 63;
        const int node = dstBase + dl;
        const int cntv = counts[node];
        const float cl = fmaxf((float)cntv, 1.f);
        const size_t off = rowbase + (size_t)node * HID + c;
        const float v = hres[off] + hacc[i] / cl + (cntv > 0 ? B2[c] : 0.f);
        hres[off] = v;
        hb_out[off] = f2bf(v);
    }
}

// ---------------- proj: 2 row-groups per block, fast gelu ----------------
__global__ __launch_bounds__(256) void proj_kernel(
    const ushort_t* __restrict__ hbm, const ushort_t* __restrict__ pfrag,
    const float* __restrict__ b1, const float* __restrict__ w2,
    const float* __restrict__ b2, float* __restrict__ out)
{
    __shared__ __align__(16) ushort_t WF[2048 * 8];

    const int tid = threadIdx.x;
    const int wv = tid >> 6;
    const int lane = tid & 63;
    const int m16 = lane & 15;
    const int q = lane >> 4;

    {
        const uint4* gw = (const uint4*)pfrag;
        uint4* lw = (uint4*)WF;
        for (int i = tid; i < 2048; i += 256) lw[i] = gw[i];
    }
    __syncthreads();

    float b1v[16], w2v[16];
#pragma unroll
    for (int ct = 0; ct < 16; ++ct) {
        b1v[ct] = b1[ct * 16 + m16];
        w2v[ct] = w2[ct * 16 + m16];
    }
    const float b2s = b2[0];

    for (int grp = 0; grp < 2; ++grp) {
        const int gid0 = (blockIdx.x * 8 + wv * 2 + grp) * 16;

        frag_u a0, a1;
        const uint4* hr = (const uint4*)(hbm + (size_t)(gid0 + m16) * HID);
        a0.u = hr[q];
        a1.u = hr[4 + q];

        floatx4 acc[16];
#pragma unroll
        for (int ct = 0; ct < 16; ++ct) {
            const short8 bf0 = *(const short8*)&WF[((size_t)(ct) * 64 + lane) * 8];
            const short8 bf1 = *(const short8*)&WF[((size_t)(16 + ct) * 64 + lane) * 8];
            floatx4 c = {0.f, 0.f, 0.f, 0.f};
            c = __builtin_amdgcn_mfma_f32_16x16x32_bf16(a0.s, bf0, c, 0, 0, 0);
            c = __builtin_amdgcn_mfma_f32_16x16x32_bf16(a1.s, bf1, c, 0, 0, 0);
            acc[ct] = c;
        }

        float p[4] = {0.f, 0.f, 0.f, 0.f};
#pragma unroll
        for (int ct = 0; ct < 16; ++ct)
#pragma unroll
            for (int r = 0; r < 4; ++r)
                p[r] += gelu_fast(acc[ct][r] + b1v[ct]) * w2v[ct];

#pragma unroll
        for (int r = 0; r < 4; ++r) {
            p[r] += __shfl_xor(p[r], 1);
            p[r] += __shfl_xor(p[r], 2);
            p[r] += __shfl_xor(p[r], 4);
            p[r] += __shfl_xor(p[r], 8);
        }
        if (m16 == 0) {
#pragma unroll
            for (int r = 0; r < 4; ++r)
                out[gid0 + q * 4 + r] = p[r] + b2s;
        }
    }
}

extern "C" void kernel_launch(void* const* d_in, const int* in_sizes, int n_in,
                              void* d_out, int out_size, void* d_ws, size_t ws_size,
                              hipStream_t stream)
{
    const float* x        = (const float*)d_in[0];
    const float* pos      = (const float*)d_in[1];
    const int*   ei       = (const int*)d_in[2];
    const float* lift_w1  = (const float*)d_in[3];
    const float* lift_b1  = (const float*)d_in[4];
    const float* lift_w2  = (const float*)d_in[5];
    const float* lift_b2  = (const float*)d_in[6];
    const float* kW1      = (const float*)d_in[7];
    const float* kb1      = (const float*)d_in[8];
    const float* kW2      = (const float*)d_in[9];
    const float* kb2      = (const float*)d_in[10];
    const float* proj_w1  = (const float*)d_in[11];
    const float* proj_b1  = (const float*)d_in[12];
    const float* proj_w2  = (const float*)d_in[13];
    const float* proj_b2  = (const float*)d_in[14];
    float* out = (float*)d_out;

    char* ws = (char*)d_ws;
    size_t off = 0;
    float*    hres  = (float*)(ws + off);    off += (size_t)BATCH * N_POINTS * HID * 4;  // 16MB
    ushort_t* hbA   = (ushort_t*)(ws + off); off += (size_t)BATCH * N_POINTS * HID * 2;  // 8MB
    ushort_t* hbB   = (ushort_t*)(ws + off); off += (size_t)BATCH * N_POINTS * HID * 2;  // 8MB
    int* counts     = (int*)(ws + off);      off += (size_t)N_POINTS * 4;
    int* row_start  = (int*)(ws + off);      off += (size_t)(N_POINTS + 4) * 4;
    int* cursor     = (int*)(ws + off);      off += (size_t)N_POINTS * 4;   // dead after fill; wfrag aliases
    int2* csr_pair  = (int2*)(ws + off);     off += (size_t)N_EDGES * 8;    // pfrag aliases after layers
    ushort_t* wfrag = (ushort_t*)cursor;
    ushort_t* pfrag = (ushort_t*)csr_pair;

    hipMemsetAsync(counts, 0, N_POINTS * 4, stream);
    hipMemsetAsync(cursor, 0, N_POINTS * 4, stream);

    hist_kernel<<<N_EDGES / 256, 256, 0, stream>>>(ei, counts);
    scan_kernel<<<1, 1024, 0, stream>>>(counts, row_start);
    fill_kernel<<<N_EDGES / 256, 256, 0, stream>>>(ei, row_start, cursor, csr_pair);
    wprep_kernel<<<(FR_TOT * 64) / 256, 256, 0, stream>>>(
        kW1, kb1, kW2, lift_w1, lift_b1, lift_w2, wfrag);

    lift_kernel<<<BATCH * N_POINTS / 128, 256, 0, stream>>>(x, pos, wfrag, lift_b2, hres, hbA);

    ushort_t* hin = hbA;
    ushort_t* hout = hbB;
    for (int l = 0; l < NLAYERS; ++l) {
        layer_kernel<<<dim3(N_POINTS / DSTS, BATCH), 256, 0, stream>>>(
            hres, hin, hout, pos, csr_pair, row_start, counts,
            wfrag + (size_t)l * 20 * 64 * 8, kb2 + (size_t)l * HID);
        ushort_t* tmp = hin; hin = hout; hout = tmp;
    }

    wprep_proj_kernel<<<(32 * 64) / 256, 256, 0, stream>>>(proj_w1, pfrag);
    proj_kernel<<<BATCH * N_POINTS / 128, 256, 0, stream>>>(
        hin, pfrag, proj_b1, proj_w2, proj_b2, out);
}

// Round 15
// 590.962 us; speedup vs baseline: 1.0309x; 1.0309x over previous
//
#include <hip/hip_runtime.h>
#include <cstdint>
#include <cstddef>

#define N_POINTS 32768
#define KDEG 16
#define N_EDGES (N_POINTS*KDEG)
#define BATCH 2
#define HID 64
#define LIFTD 256
#define PROJD 256
#define KIN 68
#define NLAYERS 4

#define DSTS 32          // dst nodes per block (exclusively owned -> LDS-only aggregation)
#define LK_WAVES 4
#define GSTR 72          // ushort stride of layer G tile (144 B rows, 16B-aligned)
#define MSTR 65          // float stride of M tile

#define LASTR 40         // lift A tile stride
#define LGSTR 264        // lift G tile stride

#define FR_EDGE 0        // 80 frags (4 layers x 20): B-operand edge-MLP weights
#define FR_LW1  80       // 16 frags: lift W1'
#define FR_LW2  96       // 32 frags: lift W2'
#define FR_TOT  128      // 128KB == cursor region exactly

typedef unsigned short ushort_t;
typedef short short8 __attribute__((ext_vector_type(8)));
typedef float floatx4 __attribute__((ext_vector_type(4)));

union frag_u { uint4 u; short8 s; };

// tanh-form GELU with HW approx reciprocal (validated R11)
__device__ __forceinline__ float gelu_fast(float x) {
    float t = x * x;
    float inner = x * fmaf(0.044715f, t, 1.0f);
    float e = __expf(-1.5957691216f * inner);
#if __has_builtin(__builtin_amdgcn_rcpf)
    return x * __builtin_amdgcn_rcpf(1.0f + e);
#else
    return x * __frcp_rn(1.0f + e);
#endif
}

// round-half-up bf16 (2 ops; validated R12)
__device__ __forceinline__ ushort_t f2bf(float x) {
    return (ushort_t)((__float_as_uint(x) + 0x8000u) >> 16);
}
__device__ __forceinline__ unsigned int pk2bf(float a, float b) {
    return (unsigned int)f2bf(a) | ((unsigned int)f2bf(b) << 16);
}

// ---------------- CSR build ----------------
__global__ void hist_kernel(const int* __restrict__ ei, int* __restrict__ counts) {
    int e = blockIdx.x * 256 + threadIdx.x;
    if (e < N_EDGES) atomicAdd(&counts[ei[N_EDGES + e]], 1);
}

__global__ void scan_kernel(const int* __restrict__ counts, int* __restrict__ row_start) {
    __shared__ int sums[1024];
    const int tid = threadIdx.x;
    const int base = tid * 32;
    int s = 0;
    for (int i = 0; i < 32; ++i) s += counts[base + i];
    sums[tid] = s;
    __syncthreads();
    const int own = s;
    for (int off = 1; off < 1024; off <<= 1) {
        int v = (tid >= off) ? sums[tid - off] : 0;
        __syncthreads();
        sums[tid] += v;
        __syncthreads();
    }
    int run = sums[tid] - own;
    for (int i = 0; i < 32; ++i) { row_start[base + i] = run; run += counts[base + i]; }
    if (tid == 1023) row_start[N_POINTS] = N_EDGES;
}

__global__ void fill_kernel(const int* __restrict__ ei, const int* __restrict__ row_start,
                            int* __restrict__ cursor, int2* __restrict__ csr_pair) {
    int e = blockIdx.x * 256 + threadIdx.x;
    if (e < N_EDGES) {
        int s = ei[e], d = ei[N_EDGES + e];
        int p = atomicAdd(&cursor[d], 1);
        csr_pair[row_start[d] + p] = make_int2(s, d);
    }
}

// -------- weight pre-swizzle (bf16), B-operand layout (validated R7/R8) --------
__global__ void wprep_kernel(const float* __restrict__ kW1, const float* __restrict__ kb1,
                             const float* __restrict__ kW2,
                             const float* __restrict__ lw1, const float* __restrict__ lb1,
                             const float* __restrict__ lw2,
                             ushort_t* __restrict__ wfrag) {
    int t = blockIdx.x * 256 + threadIdx.x;
    if (t >= FR_TOT * 64) return;
    const int lane = t & 63;
    const int fi = t >> 6;
    const int m16 = lane & 15;
    const int qb = ((lane >> 4) & 3) * 8;
    ushort_t o[8];
    if (fi < FR_LW1) {
        const int l = fi / 20, f = fi % 20;
        const int n = ((f < 12 ? (f & 3) : ((f - 12) & 3)) * 16) + m16;
        if (f < 12) {
            const int kc = f >> 2;
            const float* W1 = kW1 + (size_t)l * KIN * HID;
            const float* B1 = kb1 + (size_t)l * HID;
#pragma unroll
            for (int j = 0; j < 8; ++j) {
                const int k = kc * 32 + qb + j;
                float v;
                if (k < 64) v = W1[(size_t)(4 + k) * HID + n];
                else if (k < 68) v = W1[(size_t)(k - 64) * HID + n];
                else if (k == 68) v = B1[n];
                else v = 0.f;
                o[j] = f2bf(v);
            }
        } else {
            const int kc = (f - 12) >> 2;
            const float* W2 = kW2 + (size_t)l * HID * HID;
#pragma unroll
            for (int j = 0; j < 8; ++j)
                o[j] = f2bf(W2[(size_t)(kc * 32 + qb + j) * HID + n]);
        }
    } else if (fi < FR_LW2) {
        const int ct = fi - FR_LW1;
        const int n = ct * 16 + m16;
#pragma unroll
        for (int j = 0; j < 8; ++j) {
            const int k = qb + j;
            float v;
            if (k < 5) v = lw1[(size_t)k * LIFTD + n];
            else if (k == 5) v = lb1[n];
            else v = 0.f;
            o[j] = f2bf(v);
        }
    } else {
        const int idx = fi - FR_LW2;
        const int kc = idx >> 2, ct = idx & 3;
        const int n = ct * 16 + m16;
#pragma unroll
        for (int j = 0; j < 8; ++j)
            o[j] = f2bf(lw2[(size_t)(kc * 32 + qb + j) * HID + n]);
    }
    ushort_t* dst = wfrag + ((size_t)fi * 64 + lane) * 8;
#pragma unroll
    for (int j = 0; j < 8; ++j) dst[j] = o[j];
}

__global__ void wprep_proj_kernel(const float* __restrict__ pw1, ushort_t* __restrict__ pfrag) {
    int t = blockIdx.x * 256 + threadIdx.x;
    if (t >= 32 * 64) return;
    const int lane = t & 63;
    const int fi = t >> 6;
    const int kc = fi >> 4, ct = fi & 15;
    const int n = ct * 16 + (lane & 15);
    const int qb = ((lane >> 4) & 3) * 8;
    ushort_t* dst = pfrag + ((size_t)fi * 64 + lane) * 8;
#pragma unroll
    for (int j = 0; j < 8; ++j)
        dst[j] = f2bf(pw1[(size_t)(kc * 32 + qb + j) * PROJD + n]);
}

// ---------------- lift (MFMA): 2 row-groups per block, 512 blocks ----------------
__global__ __launch_bounds__(256) void lift_kernel(
    const float* __restrict__ x, const float* __restrict__ pos,
    const ushort_t* __restrict__ wfrag, const float* __restrict__ lb2,
    float* __restrict__ hres, ushort_t* __restrict__ hb16)
{
    __shared__ __align__(16) ushort_t WF[3072 * 8];
    __shared__ __align__(16) ushort_t LA[4][16 * LASTR];
    __shared__ __align__(16) ushort_t LG[4][16 * LGSTR];

    const int tid = threadIdx.x;
    const int wv = tid >> 6;
    const int lane = tid & 63;
    const int m16 = lane & 15;
    const int q = lane >> 4;

    {
        const uint4* gw = (const uint4*)(wfrag + (size_t)FR_LW1 * 64 * 8);
        uint4* lw = (uint4*)WF;
        for (int i = tid; i < 3072; i += 256) lw[i] = gw[i];
    }
    __syncthreads();

    ushort_t* At = &LA[wv][0];
    ushort_t* Gt = &LG[wv][0];

    float b2r[4];
#pragma unroll
    for (int ct = 0; ct < 4; ++ct) b2r[ct] = lb2[ct * 16 + m16];

    for (int grp = 0; grp < 2; ++grp) {
        const int gid0 = (blockIdx.x * 8 + wv * 2 + grp) * 16;

        if (lane < 16) {
            const int g = gid0 + lane;
            const int i = g & (N_POINTS - 1);
            const float x0 = x[3 * (size_t)g], x1 = x[3 * (size_t)g + 1], x2 = x[3 * (size_t)g + 2];
            const float2 p = *(const float2*)(pos + 2 * i);
            uint4 w;
            w.x = pk2bf(x0, x1);
            w.y = pk2bf(x2, p.x);
            w.z = pk2bf(p.y, 1.0f);
            w.w = 0u;
            uint4 z; z.x = z.y = z.z = z.w = 0u;
            *(uint4*)&At[lane * LASTR + 0] = w;
            *(uint4*)&At[lane * LASTR + 8] = z;
            *(uint4*)&At[lane * LASTR + 16] = z;
            *(uint4*)&At[lane * LASTR + 24] = z;
        }

        const short8 a = *(const short8*)&At[m16 * LASTR + q * 8];
        floatx4 acc[16];
#pragma unroll
        for (int ct = 0; ct < 16; ++ct) {
            const short8 bf = *(const short8*)&WF[((size_t)ct * 64 + lane) * 8];
            floatx4 c = {0.f, 0.f, 0.f, 0.f};
            acc[ct] = __builtin_amdgcn_mfma_f32_16x16x32_bf16(a, bf, c, 0, 0, 0);
        }

#pragma unroll
        for (int ct = 0; ct < 16; ++ct)
#pragma unroll
            for (int r = 0; r < 4; ++r)
                Gt[(q * 4 + r) * LGSTR + ct * 16 + m16] = f2bf(gelu_fast(acc[ct][r]));

        floatx4 acc2[4];
#pragma unroll
        for (int ct = 0; ct < 4; ++ct) { floatx4 z = {0.f, 0.f, 0.f, 0.f}; acc2[ct] = z; }
#pragma unroll
        for (int kc = 0; kc < 8; ++kc) {
            const short8 g = *(const short8*)&Gt[m16 * LGSTR + kc * 32 + q * 8];
#pragma unroll
            for (int ct = 0; ct < 4; ++ct) {
                const short8 bf = *(const short8*)&WF[((size_t)(1024 + (kc * 4 + ct) * 64) + lane) * 8];
                acc2[ct] = __builtin_amdgcn_mfma_f32_16x16x32_bf16(g, bf, acc2[ct], 0, 0, 0);
            }
        }

#pragma unroll
        for (int ct = 0; ct < 4; ++ct)
#pragma unroll
            for (int r = 0; r < 4; ++r) {
                const float v = acc2[ct][r] + b2r[ct];
                const size_t idx = (size_t)(gid0 + q * 4 + r) * HID + ct * 16 + m16;
                hres[idx] = v;
                hb16[idx] = f2bf(v);
            }
    }
}

// ------- message-passing layer: R8 structure, b2 folded into writeout (R12 = best measured) -------
__global__ __launch_bounds__(256, 4) void layer_kernel(
    float* __restrict__ hres,
    const ushort_t* __restrict__ hb_in,
    ushort_t* __restrict__ hb_out,
    const float* __restrict__ pos,
    const int2* __restrict__ csr_pair,
    const int* __restrict__ row_start, const int* __restrict__ counts,
    const ushort_t* __restrict__ wfrag, const float* __restrict__ B2)
{
    __shared__ __align__(16) float GMt[LK_WAVES][16 * MSTR];   // 16.6 KB (G bf16 overlays M f32)
    __shared__ float hacc[DSTS * HID];                         // 8 KB
    __shared__ int   segb[LK_WAVES][16];

    const int b = blockIdx.y;
    const int dstBase = blockIdx.x * DSTS;
    const int tid = threadIdx.x;
    const int wv = tid >> 6;
    const int lane = tid & 63;
    const int m16 = lane & 15;
    const int q = lane >> 4;
    const int ch = lane & 3;
    const int growL = lane >> 2;
    const int permSrc = m16 * 4 + q;

    for (int i = tid; i < DSTS * HID; i += 256) hacc[i] = 0.f;

    const short8* wf = (const short8*)wfrag;
    short8 w1f[3][4], w2f[2][4];
#pragma unroll
    for (int kc = 0; kc < 3; ++kc)
#pragma unroll
        for (int ct = 0; ct < 4; ++ct) w1f[kc][ct] = wf[(kc * 4 + ct) * 64 + lane];
#pragma unroll
    for (int kc = 0; kc < 2; ++kc)
#pragma unroll
        for (int ct = 0; ct < 4; ++ct) w2f[kc][ct] = wf[(12 + kc * 4 + ct) * 64 + lane];
    __syncthreads();

    const int estart = row_start[dstBase];
    const int eend   = row_start[dstBase + DSTS];
    const int ntiles = (eend - estart + 15) >> 4;
    const int elast  = (eend > 0) ? (eend - 1) : 0;
    const ushort_t* __restrict__ hb = hb_in + (size_t)b * N_POINTS * HID;

    float* GM = &GMt[wv][0];
    ushort_t* Gt = (ushort_t*)GM;

    frag_u hC0, hC1; uint4 pwC; int segC;
    {
        const int e0 = estart + wv * 16;
        const int2 pA = csr_pair[min(e0 + growL, elast)];
        const int2 pB = csr_pair[min(e0 + m16, elast)];
        const uint4* hr = (const uint4*)(hb + (size_t)pA.x * HID);
        hC0.u = hr[ch];
        hC1.u = hr[ch + 4];
        const float2 ps = *(const float2*)(pos + 2 * pB.x);
        const float2 pd = *(const float2*)(pos + 2 * pB.y);
        pwC.x = pk2bf(ps.x, ps.y);
        pwC.y = pk2bf(pd.x, pd.y);
        pwC.z = 0x00003F80u;   // (1.0, 0)
        pwC.w = 0u;
        segC = (e0 + m16 < eend) ? (pB.y - dstBase) : -1;
    }

    for (int t = wv; t < ntiles; t += LK_WAVES) {
        frag_u hN0, hN1; uint4 pwN; int segN;
        {
            const int e0n = estart + (t + LK_WAVES) * 16;
            const int2 pA = csr_pair[min(e0n + growL, elast)];
            const int2 pB = csr_pair[min(e0n + m16, elast)];
            const uint4* hr = (const uint4*)(hb + (size_t)pA.x * HID);
            hN0.u = hr[ch];
            hN1.u = hr[ch + 4];
            const float2 ps = *(const float2*)(pos + 2 * pB.x);
            const float2 pd = *(const float2*)(pos + 2 * pB.y);
            pwN.x = pk2bf(ps.x, ps.y);
            pwN.y = pk2bf(pd.x, pd.y);
            pwN.z = 0x00003F80u;
            pwN.w = 0u;
            segN = (e0n + m16 < eend) ? (pB.y - dstBase) : -1;
        }

        if (lane < 16) segb[wv][lane] = segC;

        frag_u a0, a1, a2;
        a0.u.x = (unsigned)__shfl((int)hC0.u.x, permSrc);
        a0.u.y = (unsigned)__shfl((int)hC0.u.y, permSrc);
        a0.u.z = (unsigned)__shfl((int)hC0.u.z, permSrc);
        a0.u.w = (unsigned)__shfl((int)hC0.u.w, permSrc);
        a1.u.x = (unsigned)__shfl((int)hC1.u.x, permSrc);
        a1.u.y = (unsigned)__shfl((int)hC1.u.y, permSrc);
        a1.u.z = (unsigned)__shfl((int)hC1.u.z, permSrc);
        a1.u.w = (unsigned)__shfl((int)hC1.u.w, permSrc);
        if (q == 0) { a2.u = pwC; }
        else        { a2.u.x = 0u; a2.u.y = 0u; a2.u.z = 0u; a2.u.w = 0u; }

        floatx4 acc[4];
#pragma unroll
        for (int ct = 0; ct < 4; ++ct) {
            floatx4 c = {0.f, 0.f, 0.f, 0.f};
            c = __builtin_amdgcn_mfma_f32_16x16x32_bf16(a0.s, w1f[0][ct], c, 0, 0, 0);
            c = __builtin_amdgcn_mfma_f32_16x16x32_bf16(a1.s, w1f[1][ct], c, 0, 0, 0);
            c = __builtin_amdgcn_mfma_f32_16x16x32_bf16(a2.s, w1f[2][ct], c, 0, 0, 0);
            acc[ct] = c;
        }

#pragma unroll
        for (int ct = 0; ct < 4; ++ct)
#pragma unroll
            for (int r = 0; r < 4; ++r)
                Gt[(q * 4 + r) * GSTR + ct * 16 + m16] = f2bf(gelu_fast(acc[ct][r]));

        short8 g0 = *(const short8*)&Gt[m16 * GSTR +  0 + q * 8];
        short8 g1 = *(const short8*)&Gt[m16 * GSTR + 32 + q * 8];
        floatx4 mm[4];
#pragma unroll
        for (int ct = 0; ct < 4; ++ct) {
            floatx4 c = {0.f, 0.f, 0.f, 0.f};
            c = __builtin_amdgcn_mfma_f32_16x16x32_bf16(g0, w2f[0][ct], c, 0, 0, 0);
            c = __builtin_amdgcn_mfma_f32_16x16x32_bf16(g1, w2f[1][ct], c, 0, 0, 0);
            mm[ct] = c;
        }

#pragma unroll
        for (int ct = 0; ct < 4; ++ct)
#pragma unroll
            for (int r = 0; r < 4; ++r)
                GM[(q * 4 + r) * MSTR + ct * 16 + m16] = mm[ct][r];

        {
            float racc = 0.f;
            int rseg = -1;
#pragma unroll
            for (int r = 0; r < 16; ++r) {
                const int s = segb[wv][r];
                const float v = GM[r * MSTR + lane];
                if (s != rseg) {
                    if (rseg >= 0) atomicAdd(&hacc[rseg * HID + lane], racc);
                    rseg = s;
                    racc = v;
                } else {
                    racc += v;
                }
            }
            if (rseg >= 0) atomicAdd(&hacc[rseg * HID + lane], racc);
        }

        hC0 = hN0; hC1 = hN1; pwC = pwN; segC = segN;
    }
    __syncthreads();

    const size_t rowbase = (size_t)b * N_POINTS * HID;
    for (int i = tid; i < DSTS * HID; i += 256) {
        const int dl = i >> 6, c = i & 63;
        const int node = dstBase + dl;
        const int cntv = counts[node];
        const float cl = fmaxf((float)cntv, 1.f);
        const size_t off = rowbase + (size_t)node * HID + c;
        const float v = hres[off] + hacc[i] / cl + (cntv > 0 ? B2[c] : 0.f);
        hres[off] = v;
        hb_out[off] = f2bf(v);
    }
}

// ---------------- proj: 2 row-groups per block, fast gelu ----------------
__global__ __launch_bounds__(256) void proj_kernel(
    const ushort_t* __restrict__ hbm, const ushort_t* __restrict__ pfrag,
    const float* __restrict__ b1, const float* __restrict__ w2,
    const float* __restrict__ b2, float* __restrict__ out)
{
    __shared__ __align__(16) ushort_t WF[2048 * 8];

    const int tid = threadIdx.x;
    const int wv = tid >> 6;
    const int lane = tid & 63;
    const int m16 = lane & 15;
    const int q = lane >> 4;

    {
        const uint4* gw = (const uint4*)pfrag;
        uint4* lw = (uint4*)WF;
        for (int i = tid; i < 2048; i += 256) lw[i] = gw[i];
    }
    __syncthreads();

    float b1v[16], w2v[16];
#pragma unroll
    for (int ct = 0; ct < 16; ++ct) {
        b1v[ct] = b1[ct * 16 + m16];
        w2v[ct] = w2[ct * 16 + m16];
    }
    const float b2s = b2[0];

    for (int grp = 0; grp < 2; ++grp) {
        const int gid0 = (blockIdx.x * 8 + wv * 2 + grp) * 16;

        frag_u a0, a1;
        const uint4* hr = (const uint4*)(hbm + (size_t)(gid0 + m16) * HID);
        a0.u = hr[q];
        a1.u = hr[4 + q];

        floatx4 acc[16];
#pragma unroll
        for (int ct = 0; ct < 16; ++ct) {
            const short8 bf0 = *(const short8*)&WF[((size_t)(ct) * 64 + lane) * 8];
            const short8 bf1 = *(const short8*)&WF[((size_t)(16 + ct) * 64 + lane) * 8];
            floatx4 c = {0.f, 0.f, 0.f, 0.f};
            c = __builtin_amdgcn_mfma_f32_16x16x32_bf16(a0.s, bf0, c, 0, 0, 0);
            c = __builtin_amdgcn_mfma_f32_16x16x32_bf16(a1.s, bf1, c, 0, 0, 0);
            acc[ct] = c;
        }

        float p[4] = {0.f, 0.f, 0.f, 0.f};
#pragma unroll
        for (int ct = 0; ct < 16; ++ct)
#pragma unroll
            for (int r = 0; r < 4; ++r)
                p[r] += gelu_fast(acc[ct][r] + b1v[ct]) * w2v[ct];

#pragma unroll
        for (int r = 0; r < 4; ++r) {
            p[r] += __shfl_xor(p[r], 1);
            p[r] += __shfl_xor(p[r], 2);
            p[r] += __shfl_xor(p[r], 4);
            p[r] += __shfl_xor(p[r], 8);
        }
        if (m16 == 0) {
#pragma unroll
            for (int r = 0; r < 4; ++r)
                out[gid0 + q * 4 + r] = p[r] + b2s;
        }
    }
}

extern "C" void kernel_launch(void* const* d_in, const int* in_sizes, int n_in,
                              void* d_out, int out_size, void* d_ws, size_t ws_size,
                              hipStream_t stream)
{
    const float* x        = (const float*)d_in[0];
    const float* pos      = (const float*)d_in[1];
    const int*   ei       = (const int*)d_in[2];
    const float* lift_w1  = (const float*)d_in[3];
    const float* lift_b1  = (const float*)d_in[4];
    const float* lift_w2  = (const float*)d_in[5];
    const float* lift_b2  = (const float*)d_in[6];
    const float* kW1      = (const float*)d_in[7];
    const float* kb1      = (const float*)d_in[8];
    const float* kW2      = (const float*)d_in[9];
    const float* kb2      = (const float*)d_in[10];
    const float* proj_w1  = (const float*)d_in[11];
    const float* proj_b1  = (const float*)d_in[12];
    const float* proj_w2  = (const float*)d_in[13];
    const float* proj_b2  = (const float*)d_in[14];
    float* out = (float*)d_out;

    char* ws = (char*)d_ws;
    size_t off = 0;
    float*    hres  = (float*)(ws + off);    off += (size_t)BATCH * N_POINTS * HID * 4;  // 16MB
    ushort_t* hbA   = (ushort_t*)(ws + off); off += (size_t)BATCH * N_POINTS * HID * 2;  // 8MB
    ushort_t* hbB   = (ushort_t*)(ws + off); off += (size_t)BATCH * N_POINTS * HID * 2;  // 8MB
    int* counts     = (int*)(ws + off);      off += (size_t)N_POINTS * 4;
    int* row_start  = (int*)(ws + off);      off += (size_t)(N_POINTS + 4) * 4;
    int* cursor     = (int*)(ws + off);      off += (size_t)N_POINTS * 4;   // dead after fill; wfrag aliases
    int2* csr_pair  = (int2*)(ws + off);     off += (size_t)N_EDGES * 8;    // pfrag aliases after layers
    ushort_t* wfrag = (ushort_t*)cursor;
    ushort_t* pfrag = (ushort_t*)csr_pair;

    hipMemsetAsync(counts, 0, N_POINTS * 4, stream);
    hipMemsetAsync(cursor, 0, N_POINTS * 4, stream);

    hist_kernel<<<N_EDGES / 256, 256, 0, stream>>>(ei, counts);
    scan_kernel<<<1, 1024, 0, stream>>>(counts, row_start);
    fill_kernel<<<N_EDGES / 256, 256, 0, stream>>>(ei, row_start, cursor, csr_pair);
    wprep_kernel<<<(FR_TOT * 64) / 256, 256, 0, stream>>>(
        kW1, kb1, kW2, lift_w1, lift_b1, lift_w2, wfrag);

    lift_kernel<<<BATCH * N_POINTS / 128, 256, 0, stream>>>(x, pos, wfrag, lift_b2, hres, hbA);

    ushort_t* hin = hbA;
    ushort_t* hout = hbB;
    for (int l = 0; l < NLAYERS; ++l) {
        layer_kernel<<<dim3(N_POINTS / DSTS, BATCH), 256, 0, stream>>>(
            hres, hin, hout, pos, csr_pair, row_start, counts,
            wfrag + (size_t)l * 20 * 64 * 8, kb2 + (size_t)l * HID);
        ushort_t* tmp = hin; hin = hout; hout = tmp;
    }

    wprep_proj_kernel<<<(32 * 64) / 256, 256, 0, stream>>>(proj_w1, pfrag);
    proj_kernel<<<BATCH * N_POINTS / 128, 256, 0, stream>>>(
        hin, pfrag, proj_b1, proj_w2, proj_b2, out);
}